// Round 9
// baseline (1353.952 us; speedup 1.0000x reference)
//
#include <hip/hip_runtime.h>
#include <hip/hip_bf16.h>

#define N_NODES 100000
#define N_EDGES 400000
#define F_NODE_ 64
#define F_EDGE_ 16
#define HID_ 128
#define N_GRAPH 1024
#define N_TASK 5

typedef unsigned short u16;
typedef __attribute__((ext_vector_type(8))) short frag8;   // 8 bf16 = 4 VGPRs
typedef __attribute__((ext_vector_type(4))) float f32x4;   // MFMA C/D

__device__ __forceinline__ float bu2f(u16 v){ return __uint_as_float(((unsigned)v) << 16); }
__device__ __forceinline__ float2 bp2f(unsigned u){
  return make_float2(__uint_as_float(u << 16), __uint_as_float(u & 0xFFFF0000u));
}
__device__ __forceinline__ u16 f2bu(float f){
  __hip_bfloat16 h = __float2bfloat16(f);
  return *(u16*)&h;
}

// ---------------- cast f32 -> bf16 ----------------
__global__ __launch_bounds__(256) void k_cast(const float* __restrict__ s, u16* __restrict__ d, int n){
  int i = blockIdx.x*256 + threadIdx.x;
  if (i < n) d[i] = f2bu(s[i]);
}

// ---------------- pre-swizzle [Wl|Wr] (K x 128 each, f32) into B-fragment order, bf16 ----------------
// B-frag (verified R7): lane = quad*16 + (n&15), elem j = k&7, quad = (k&31)>>3, chunk c = k>>5
// Wz[(((c*16 + nt)*64) + lane)*8 + j], nt = which*8 + (n>>4)
__global__ __launch_bounds__(256) void k_wswz2(const float* __restrict__ Wl,
                                               const float* __restrict__ Wr,
                                               u16* __restrict__ Wz, int K){
  int i = blockIdx.x*256 + threadIdx.x;
  if (i >= K*256) return;
  int k = i >> 8, n2 = i & 255;
  int which = n2 >> 7, n = n2 & 127;
  const float* src = which ? Wr : Wl;
  int kk = k & 31, c = k >> 5;
  int quad = kk >> 3, j = kk & 7;
  int nt = which*8 + (n >> 4);
  int lane = quad*16 + (n & 15);
  Wz[(((c*16 + nt)*64) + lane)*8 + j] = f2bu(src[k*128 + n]);
}

// ---------------- LDS-free dual MFMA GEMM: [xl|xr] = A @ [Wl|Wr] + bias ----------------
// block 256 = 4 waves; wave handles 16 rows x 256 cols (16 n-tiles); grid = ceil(M/64)
__global__ __launch_bounds__(256) void k_gemm2(const u16* __restrict__ A,
                                               const u16* __restrict__ Wz,
                                               const float* __restrict__ bl,
                                               const float* __restrict__ br,
                                               u16* __restrict__ Cl,
                                               u16* __restrict__ Cr,
                                               int M, int K){
  const int t = threadIdx.x;
  const int w = t >> 6, l = t & 63;
  const int m = l & 15, quad = l >> 4;
  const int row0 = blockIdx.x*64 + w*16 + m;
  f32x4 acc[16];
  #pragma unroll
  for (int i=0;i<16;i++) acc[i] = (f32x4){0.f,0.f,0.f,0.f};
  const int KC = K >> 5;
  for (int c = 0; c < KC; c++){
    frag8 a = {};
    if (row0 < M) a = *(const frag8*)(A + (size_t)row0*K + c*32 + quad*8);
    #pragma unroll
    for (int nt = 0; nt < 16; nt++){
      frag8 b = *(const frag8*)&Wz[(((c*16 + nt)*64) + l)*8];
      acc[nt] = __builtin_amdgcn_mfma_f32_16x16x32_bf16(a, b, acc[nt], 0,0,0);
    }
  }
  const int rbase = blockIdx.x*64 + w*16 + quad*4;
  #pragma unroll
  for (int nt = 0; nt < 8; nt++){
    int col = nt*16 + m;
    float bc = bl[col];
    #pragma unroll
    for (int r = 0; r < 4; r++){
      int row = rbase + r;
      if (row < M) Cl[(size_t)row*128 + col] = f2bu(acc[nt][r] + bc);
    }
  }
  #pragma unroll
  for (int nt = 8; nt < 16; nt++){
    int col = (nt-8)*16 + m;
    float bc = br[col];
    #pragma unroll
    for (int r = 0; r < 4; r++){
      int row = rbase + r;
      if (row < M) Cr[(size_t)row*128 + col] = f2bu(acc[nt][r] + bc);
    }
  }
}

// ---------------- CSR build (once; topology shared by all 4 layers) ----------------
__global__ __launch_bounds__(256) void k_hist(const int* __restrict__ ei, int* __restrict__ counts){
  int e = blockIdx.x*256 + threadIdx.x;
  if (e < N_EDGES) atomicAdd(&counts[ei[N_EDGES + e]], 1);
}

__global__ __launch_bounds__(512) void k_scan1(const int* __restrict__ counts,
                                               int* __restrict__ incl,
                                               int* __restrict__ bsum){
  __shared__ int s[512];
  const int t = threadIdx.x;
  int i = blockIdx.x*512 + t;
  int v = (i < N_NODES) ? counts[i] : 0;
  s[t] = v;
  __syncthreads();
  for (int off = 1; off < 512; off <<= 1){
    int x = (t >= off) ? s[t - off] : 0;
    __syncthreads();
    s[t] += x;
    __syncthreads();
  }
  if (i < N_NODES) incl[i] = s[t];
  if (t == 511) bsum[blockIdx.x] = s[511];
}

__global__ __launch_bounds__(256) void k_scan2(int* __restrict__ bsum, int nb){
  __shared__ int s[256];
  const int t = threadIdx.x;
  int v = (t < nb) ? bsum[t] : 0;
  s[t] = v;
  __syncthreads();
  for (int off = 1; off < 256; off <<= 1){
    int x = (t >= off) ? s[t - off] : 0;
    __syncthreads();
    s[t] += x;
    __syncthreads();
  }
  if (t < nb) bsum[t] = s[t] - v;
}

__global__ __launch_bounds__(512) void k_scan3(const int* __restrict__ counts,
                                               const int* __restrict__ incl,
                                               const int* __restrict__ bsum,
                                               int* __restrict__ offsets,
                                               int* __restrict__ cursor){
  int i = blockIdx.x*512 + threadIdx.x;
  if (i >= N_NODES) return;
  int o = bsum[blockIdx.x] + incl[i];
  offsets[i + 1] = o;
  cursor[i]      = o - counts[i];
  if (i == 0) offsets[0] = 0;
}

// scatter: src index + edge features (f32) into CSR order
__global__ __launch_bounds__(256) void k_scatter(const int* __restrict__ ei,
                                                 int* __restrict__ cursor,
                                                 int* __restrict__ ssrc,
                                                 const float* __restrict__ ea,
                                                 float* __restrict__ ea_s){
  int e = blockIdx.x*256 + threadIdx.x;
  if (e >= N_EDGES) return;
  int dst = ei[N_EDGES + e];
  int pos = atomicAdd(&cursor[dst], 1);
  ssrc[pos] = ei[e];
  const float4* s4 = (const float4*)(ea + (size_t)e*F_EDGE_);
  float4* d4 = (float4*)(ea_s + (size_t)pos*F_EDGE_);
  d4[0] = s4[0]; d4[1] = s4[1]; d4[2] = s4[2]; d4[3] = s4[3];
}

// ---------------- Graph CSR from sorted batch (once) ----------------
__global__ __launch_bounds__(256) void k_ghist(const int* __restrict__ batch, int* __restrict__ gcnt){
  int i = blockIdx.x*256 + threadIdx.x;
  if (i < N_NODES) atomicAdd(&gcnt[batch[i]], 1);
}

__global__ __launch_bounds__(1024) void k_gscan(const int* __restrict__ gcnt, int* __restrict__ goff){
  __shared__ int s[1024];
  const int t = threadIdx.x;
  int v = gcnt[t];
  s[t] = v;
  __syncthreads();
  for (int off = 1; off < 1024; off <<= 1){
    int x = (t >= off) ? s[t - off] : 0;
    __syncthreads();
    s[t] += x;
    __syncthreads();
  }
  goff[t + 1] = s[t];
  if (t == 0) goff[0] = 0;
}

// ---------------- Fused GAT (bf16 xl/xr): per-dst-node softmax + aggregation ----------------
#define GAT_GRID 3125
__global__ __launch_bounds__(256) void k_gat(const u16* __restrict__ xl,
                                             const u16* __restrict__ xr,
                                             const float* __restrict__ ea_s,
                                             const float* __restrict__ We,
                                             const float* __restrict__ att,
                                             const int* __restrict__ offsets,
                                             const int* __restrict__ ssrc,
                                             float* __restrict__ aggr){
  __shared__ float WeS[16*128];
  __shared__ float attS[128];
  const int t = threadIdx.x;
  for (int i=t;i<16*128;i+=256) WeS[i] = We[i];
  if (t < 128) attS[t] = att[t];
  __syncthreads();
  const int wave = t >> 6, lane = t & 63;
  const int c0 = lane*2;
  const int el = lane & 15;
  const float a0 = attS[c0], a1 = attS[c0+1];
  float2 wreg[16];
  #pragma unroll
  for (int k=0;k<16;k++) wreg[k] = *(const float2*)&WeS[k*128 + c0];

  for (int node = blockIdx.x*4 + wave; node < N_NODES; node += GAT_GRID*4){
    const float2 xrv = bp2f(*(const unsigned*)(xr + (size_t)node*HID_ + c0));
    float acc0 = 0.f, acc1 = 0.f, den = 0.f;
    const int beg = offsets[node], end = offsets[node+1];
    for (int i = beg; i < end; i += 4){
      const int mm = end - i;
      const int i1 = (mm > 1) ? i+1 : i;
      const int i2 = (mm > 2) ? i+2 : i;
      const int i3 = (mm > 3) ? i+3 : i;
      int s0 = ssrc[i], s1 = ssrc[i1], s2 = ssrc[i2], s3 = ssrc[i3];
      float av0 = ea_s[(size_t)i *F_EDGE_ + el];
      float av1 = ea_s[(size_t)i1*F_EDGE_ + el];
      float av2 = ea_s[(size_t)i2*F_EDGE_ + el];
      float av3 = ea_s[(size_t)i3*F_EDGE_ + el];
      float2 vl0 = bp2f(*(const unsigned*)(xl + (size_t)s0*HID_ + c0));
      float2 vl1 = bp2f(*(const unsigned*)(xl + (size_t)s1*HID_ + c0));
      float2 vl2 = bp2f(*(const unsigned*)(xl + (size_t)s2*HID_ + c0));
      float2 vl3 = bp2f(*(const unsigned*)(xl + (size_t)s3*HID_ + c0));
      float e00=0.f,e01=0.f,e10=0.f,e11=0.f,e20=0.f,e21=0.f,e30=0.f,e31=0.f;
      #pragma unroll
      for (int k=0;k<16;k++){
        float b0 = __shfl(av0, k);
        float b1 = __shfl(av1, k);
        float b2 = __shfl(av2, k);
        float b3 = __shfl(av3, k);
        e00 += b0*wreg[k].x; e01 += b0*wreg[k].y;
        e10 += b1*wreg[k].x; e11 += b1*wreg[k].y;
        e20 += b2*wreg[k].x; e21 += b2*wreg[k].y;
        e30 += b3*wreg[k].x; e31 += b3*wreg[k].y;
      }
      float v00 = vl0.x + xrv.x + e00, v01 = vl0.y + xrv.y + e01;
      float v10 = vl1.x + xrv.x + e10, v11 = vl1.y + xrv.y + e11;
      float v20 = vl2.x + xrv.x + e20, v21 = vl2.y + xrv.y + e21;
      float v30 = vl3.x + xrv.x + e30, v31 = vl3.y + xrv.y + e31;
      v00 = v00 > 0.f ? v00 : 0.2f*v00;  v01 = v01 > 0.f ? v01 : 0.2f*v01;
      v10 = v10 > 0.f ? v10 : 0.2f*v10;  v11 = v11 > 0.f ? v11 : 0.2f*v11;
      v20 = v20 > 0.f ? v20 : 0.2f*v20;  v21 = v21 > 0.f ? v21 : 0.2f*v21;
      v30 = v30 > 0.f ? v30 : 0.2f*v30;  v31 = v31 > 0.f ? v31 : 0.2f*v31;
      float sc0 = v00*a0 + v01*a1;
      float sc1 = v10*a0 + v11*a1;
      float sc2 = v20*a0 + v21*a1;
      float sc3 = v30*a0 + v31*a1;
      sc0 += __shfl_xor(sc0, 1); sc1 += __shfl_xor(sc1, 1); sc2 += __shfl_xor(sc2, 1); sc3 += __shfl_xor(sc3, 1);
      sc0 += __shfl_xor(sc0, 2); sc1 += __shfl_xor(sc1, 2); sc2 += __shfl_xor(sc2, 2); sc3 += __shfl_xor(sc3, 2);
      sc0 += __shfl_xor(sc0, 4); sc1 += __shfl_xor(sc1, 4); sc2 += __shfl_xor(sc2, 4); sc3 += __shfl_xor(sc3, 4);
      sc0 += __shfl_xor(sc0, 8); sc1 += __shfl_xor(sc1, 8); sc2 += __shfl_xor(sc2, 8); sc3 += __shfl_xor(sc3, 8);
      float p0 = __expf(sc0);
      float p1 = (mm > 1) ? __expf(sc1) : 0.f;
      float p2 = (mm > 2) ? __expf(sc2) : 0.f;
      float p3 = (mm > 3) ? __expf(sc3) : 0.f;
      acc0 += p0*vl0.x + p1*vl1.x + p2*vl2.x + p3*vl3.x;
      acc1 += p0*vl0.y + p1*vl1.y + p2*vl2.y + p3*vl3.y;
      den  += p0 + p1 + p2 + p3;
    }
    float inv = 1.0f / (den + 1e-16f);
    *(float2*)(aggr + (size_t)node*HID_ + c0) = make_float2(acc0*inv, acc1*inv);
  }
}

// ---------------- BN stats ----------------
__global__ __launch_bounds__(256) void k_bn_stats(const float* __restrict__ aggr,
                                                  float* __restrict__ stats){
  __shared__ float redS[256], redS2[256];
  const int t = threadIdx.x;
  const int c = t & 127, half = t >> 7;
  float s = 0.f, s2 = 0.f;
  for (int r = blockIdx.x*2 + half; r < N_NODES; r += gridDim.x*2){
    float v = aggr[(size_t)r*HID_ + c];
    s += v; s2 += v*v;
  }
  redS[t] = s; redS2[t] = s2;
  __syncthreads();
  if (half == 0){
    s  += redS[t+128];
    s2 += redS2[t+128];
    atomicAdd(&stats[c], s);
    atomicAdd(&stats[128+c], s2);
  }
}

// ---------------- BN apply + ELU (+ residual), h in bf16 ----------------
__global__ __launch_bounds__(256) void k_bn_apply(const float* __restrict__ aggr,
                                                  const float* __restrict__ stats,
                                                  const float* __restrict__ gamma,
                                                  const float* __restrict__ beta,
                                                  u16* __restrict__ h, int residual){
  size_t i = (size_t)blockIdx.x*256 + threadIdx.x;
  if (i >= (size_t)N_NODES*HID_) return;
  int c = i & 127;
  const float invn = 1.0f / (float)N_NODES;
  float mu  = stats[c] * invn;
  float var = stats[128+c] * invn - mu*mu;
  float sc  = rsqrtf(var + 1e-5f) * gamma[c];
  float val = (aggr[i] - mu) * sc + beta[c];
  val = val > 0.f ? val : expm1f(val);
  if (residual) val += bu2f(h[i]);
  h[i] = f2bu(val);
}

// ---------------- Pool: segmented mean over sorted batch ----------------
__global__ __launch_bounds__(128) void k_pool_seg(const u16* __restrict__ h,
                                                  const int* __restrict__ goff,
                                                  float* __restrict__ emb){
  const int g = blockIdx.x, c = threadIdx.x;
  const int beg = goff[g], end = goff[g+1];
  float acc = 0.f;
  for (int r = beg; r < end; r++) acc += bu2f(h[(size_t)r*HID_ + c]);
  float n = (float)(end - beg);
  emb[(size_t)g*HID_ + c] = acc / fmaxf(n, 1.f);
}

// ---------------- Per-task heads ----------------
__global__ __launch_bounds__(128) void k_heads(const float* __restrict__ emb,
                                               const float* __restrict__ mf,
                                               const int* __restrict__ fpi,
                                               const float* __restrict__ tw1,
                                               const float* __restrict__ tb1,
                                               const float* __restrict__ tw2,
                                               const float* __restrict__ tb2,
                                               float* __restrict__ out){
  const int g = blockIdx.x, task = blockIdx.y;
  const int j = threadIdx.x;
  __shared__ float fused[160];
  __shared__ float red[128];
  fused[j] = emb[(size_t)g*HID_ + j];
  if (j < 32){
    int bit = fpi[task*32 + j];
    fused[128 + j] = mf[(size_t)g*2048 + bit];
  }
  __syncthreads();
  const float* w1 = tw1 + (size_t)task*160*128;
  float acc = tb1[task*128 + j];
  #pragma unroll 8
  for (int i=0;i<160;i++) acc += fused[i] * w1[(size_t)i*128 + j];
  acc = acc > 0.f ? acc : 0.f;
  acc *= tw2[task*128 + j];
  red[j] = acc;
  __syncthreads();
  for (int s=64; s>0; s>>=1){
    if (j < s) red[j] += red[j+s];
    __syncthreads();
  }
  if (j == 0) out[(size_t)g*N_TASK + task] = red[0] + tb2[task];
}

extern "C" void kernel_launch(void* const* d_in, const int* in_sizes, int n_in,
                              void* d_out, int out_size, void* d_ws, size_t ws_size,
                              hipStream_t stream){
  const float* x    = (const float*)d_in[0];
  const int*   ei   = (const int*)  d_in[1];
  const float* ea   = (const float*)d_in[2];
  const int*   batch= (const int*)  d_in[3];
  const float* mf   = (const float*)d_in[4];
  const int*   fpi  = (const int*)  d_in[5];
  const float* Wl0  = (const float*)d_in[6];
  const float* bl0  = (const float*)d_in[7];
  const float* Wr0  = (const float*)d_in[8];
  const float* br0  = (const float*)d_in[9];
  const float* We0  = (const float*)d_in[10];
  const float* att0 = (const float*)d_in[11];
  const float* g0   = (const float*)d_in[13];
  const float* b0   = (const float*)d_in[14];
  const float* Wl   = (const float*)d_in[15];
  const float* bl   = (const float*)d_in[16];
  const float* Wr   = (const float*)d_in[17];
  const float* br   = (const float*)d_in[18];
  const float* We   = (const float*)d_in[19];
  const float* att  = (const float*)d_in[20];
  const float* gg   = (const float*)d_in[22];
  const float* bb   = (const float*)d_in[23];
  const float* tw1  = (const float*)d_in[24];
  const float* tb1  = (const float*)d_in[25];
  const float* tw2  = (const float*)d_in[26];
  const float* tb2  = (const float*)d_in[27];
  float* out = (float*)d_out;

  char* w = (char*)d_ws;
  auto alloc = [&](size_t bytes)->char*{ char* r = w; w += (bytes + 255) & ~(size_t)255; return r; };
  u16*   xl     = (u16*)  alloc((size_t)N_NODES*HID_*2);
  u16*   xr     = (u16*)  alloc((size_t)N_NODES*HID_*2);
  u16*   h      = (u16*)  alloc((size_t)N_NODES*HID_*2);
  u16*   xbf    = (u16*)  alloc((size_t)N_NODES*F_NODE_*2);
  float* aggr   = (float*)alloc((size_t)N_NODES*HID_*4);
  float* stats  = (float*)alloc(256*4);
  float* emb    = (float*)alloc((size_t)N_GRAPH*HID_*4);
  int*   counts = (int*)  alloc((size_t)N_NODES*4);
  int*   offsets= (int*)  alloc((size_t)(N_NODES+1)*4);
  int*   cursor = (int*)  alloc((size_t)N_NODES*4);
  int*   incl   = (int*)  alloc((size_t)N_NODES*4);
  int*   bsum   = (int*)  alloc(256*4);
  int*   ssrc   = (int*)  alloc((size_t)N_EDGES*4);
  float* ea_s   = (float*)alloc((size_t)N_EDGES*F_EDGE_*4);
  int*   gcnt   = (int*)  alloc((size_t)N_GRAPH*4);
  int*   goff   = (int*)  alloc((size_t)(N_GRAPH+1)*4);
  u16*   Wz0    = (u16*)  alloc((size_t)F_NODE_*256*2);      // K=64 swizzled [Wl0|Wr0]
  u16*   Wz123  = (u16*)  alloc((size_t)3*HID_*256*2);       // K=128 swizzled per layer

  const int eg256 = (N_EDGES + 255)/256;
  const int ng256 = (N_NODES + 255)/256;
  const int nscan = (N_NODES + 511)/512;
  const int gemm_grid = (N_NODES + 63)/64;

  // one-time: input cast + weight pre-swizzles
  hipLaunchKernelGGL(k_cast, dim3((N_NODES*F_NODE_ + 255)/256), dim3(256), 0, stream, x, xbf, N_NODES*F_NODE_);
  hipLaunchKernelGGL(k_wswz2, dim3((F_NODE_*256 + 255)/256), dim3(256), 0, stream, Wl0, Wr0, Wz0, F_NODE_);
  for (int i=0;i<3;i++)
    hipLaunchKernelGGL(k_wswz2, dim3((HID_*256 + 255)/256), dim3(256), 0, stream,
                       Wl + (size_t)i*HID_*HID_, Wr + (size_t)i*HID_*HID_,
                       Wz123 + (size_t)i*HID_*256, HID_);

  // CSR build (topology constant across layers) + graph offsets
  hipMemsetAsync(counts, 0, (size_t)N_NODES*4, stream);
  hipMemsetAsync(gcnt,   0, (size_t)N_GRAPH*4, stream);
  hipLaunchKernelGGL(k_hist,    dim3(eg256), dim3(256), 0, stream, ei, counts);
  hipLaunchKernelGGL(k_ghist,   dim3(ng256), dim3(256), 0, stream, batch, gcnt);
  hipLaunchKernelGGL(k_scan1,   dim3(nscan), dim3(512), 0, stream, counts, incl, bsum);
  hipLaunchKernelGGL(k_scan2,   dim3(1),     dim3(256), 0, stream, bsum, nscan);
  hipLaunchKernelGGL(k_scan3,   dim3(nscan), dim3(512), 0, stream, counts, incl, bsum, offsets, cursor);
  hipLaunchKernelGGL(k_gscan,   dim3(1),     dim3(1024),0, stream, gcnt, goff);
  hipLaunchKernelGGL(k_scatter, dim3(eg256), dim3(256), 0, stream, ei, cursor, ssrc, ea, ea_s);

  for (int layer = 0; layer < 4; layer++){
    const float *bl_, *br_, *We_, *att_, *g_, *b_;
    const u16 *Wz_, *Ain;
    int K;
    if (layer == 0){
      bl_=bl0; br_=br0; We_=We0; att_=att0; g_=g0; b_=b0;
      Wz_ = Wz0; Ain = xbf; K = F_NODE_;
    } else {
      int i = layer - 1;
      bl_ = bl + (size_t)i*HID_;  br_ = br + (size_t)i*HID_;
      We_ = We + (size_t)i*F_EDGE_*HID_;
      att_= att + (size_t)i*HID_;
      g_  = gg + (size_t)i*HID_;  b_  = bb + (size_t)i*HID_;
      Wz_ = Wz123 + (size_t)i*HID_*256;
      Ain = h; K = HID_;
    }
    hipLaunchKernelGGL(k_gemm2, dim3(gemm_grid), dim3(256), 0, stream, Ain, Wz_, bl_, br_, xl, xr, N_NODES, K);
    hipMemsetAsync(stats, 0, 256*4, stream);
    hipLaunchKernelGGL(k_gat, dim3(GAT_GRID), dim3(256), 0, stream,
                       xl, xr, ea_s, We_, att_, offsets, ssrc, aggr);
    hipLaunchKernelGGL(k_bn_stats, dim3(512), dim3(256), 0, stream, aggr, stats);
    hipLaunchKernelGGL(k_bn_apply, dim3((N_NODES*HID_ + 255)/256), dim3(256), 0, stream,
                       aggr, stats, g_, b_, h, layer > 0 ? 1 : 0);
  }
  hipLaunchKernelGGL(k_pool_seg, dim3(N_GRAPH), dim3(128), 0, stream, h, goff, emb);
  hipLaunchKernelGGL(k_heads, dim3(N_GRAPH, N_TASK), dim3(128), 0, stream, emb, mf, fpi, tw1, tb1, tw2, tb2, out);
}